// Round 1
// baseline (2197.090 us; speedup 1.0000x reference)
//
#include <hip/hip_runtime.h>
#include <hip/hip_bf16.h>

// Problem constants
#define BB 32
#define LPQ 1024      // LP == LH == 1024
#define DD 256        // D == H == 256

// ---------------------------------------------------------------------------
// Kernel 1: F = tanh(A[M,256] @ W[256,256]) , fp32 tiled GEMM
// block 256 threads, tile 64x64, K-chunk 16, 4x4 micro-tile per thread
// ---------------------------------------------------------------------------
#define PROJ_BM 64
#define PROJ_BN 64
#define PROJ_BK 16
#define PROJ_LDA (PROJ_BM + 4)
#define PROJ_LDW (PROJ_BN + 4)

__global__ __launch_bounds__(256) void proj_tanh(
    const float* __restrict__ A, const float* __restrict__ W,
    float* __restrict__ C, int M) {
  __shared__ float As[PROJ_BK][PROJ_LDA];  // transposed: As[k][m]
  __shared__ float Ws[PROJ_BK][PROJ_LDW];

  const int tid = threadIdx.x;
  const int tx = tid & 15;
  const int ty = tid >> 4;
  const int row0 = blockIdx.x * PROJ_BM;
  const int col0 = blockIdx.y * PROJ_BN;

  float acc[4][4] = {};

  for (int k0 = 0; k0 < DD; k0 += PROJ_BK) {
    // A tile: 64 rows x 16 k -> thread t loads float4 of row t/4, k-chunk (t%4)*4
    {
      const int r = tid >> 2;
      const int kk = (tid & 3) * 4;
      float4 a = *(const float4*)&A[(size_t)(row0 + r) * DD + k0 + kk];
      As[kk + 0][r] = a.x;
      As[kk + 1][r] = a.y;
      As[kk + 2][r] = a.z;
      As[kk + 3][r] = a.w;
      // W tile: 16 k x 64 n
      const int wk = tid >> 4;
      const int wn = (tid & 15) * 4;
      *(float4*)&Ws[wk][wn] = *(const float4*)&W[(size_t)(k0 + wk) * DD + col0 + wn];
    }
    __syncthreads();
#pragma unroll
    for (int k = 0; k < PROJ_BK; ++k) {
      float4 a = *(const float4*)&As[k][ty * 4];
      float4 w = *(const float4*)&Ws[k][tx * 4];
      float av[4] = {a.x, a.y, a.z, a.w};
      float wv[4] = {w.x, w.y, w.z, w.w};
#pragma unroll
      for (int i = 0; i < 4; ++i)
#pragma unroll
        for (int j = 0; j < 4; ++j) acc[i][j] += av[i] * wv[j];
    }
    __syncthreads();
  }

#pragma unroll
  for (int i = 0; i < 4; ++i) {
    float4 o;
    o.x = tanhf(acc[i][0]);
    o.y = tanhf(acc[i][1]);
    o.z = tanhf(acc[i][2]);
    o.w = tanhf(acc[i][3]);
    *(float4*)&C[(size_t)(row0 + ty * 4 + i) * DD + col0 + tx * 4] = o;
  }
}

// ---------------------------------------------------------------------------
// Kernel 2: flash-style alignment:
//   Out[b,p,:] = sum_q softmax_q( Fq[b,p,:] . Fk[b,q,:] ) * V[b,q,:]
// block 256 threads = 16 p-rows x 16-lane groups; TQ=16 K/V tiles; online softmax.
// LDS ~51KB -> 3 blocks/CU.
// ---------------------------------------------------------------------------
#define AT_T 16          // tile rows for both P and Q(=K) direction
#define AT_LDS 260       // padded row stride (floats), 16B-aligned, breaks conflicts

__global__ __launch_bounds__(256) void flash_attn(
    const float* __restrict__ Fq,  // [B, LQ, 256]
    const float* __restrict__ Fk,  // [B, LK, 256]
    const float* __restrict__ V,   // [B, LK, 256]
    float* __restrict__ Out,       // [B, LQ, 256]
    int LQ, int LK) {
  __shared__ float Qs[AT_T][AT_LDS];
  __shared__ float Ks[AT_T][AT_LDS];
  __shared__ float Vs[AT_T][AT_LDS];
  __shared__ float Ss[AT_T][AT_T + 1];

  const int tid = threadIdx.x;  // 256
  const int g = tid & 15;       // lane-in-row-group
  const int p = tid >> 4;       // p-row 0..15

  const int tilesPerB = LQ / AT_T;
  const int b = blockIdx.x / tilesPerB;
  const int p0 = (blockIdx.x % tilesPerB) * AT_T;

  const float* Fq_b = Fq + ((size_t)b * LQ + p0) * DD;
  const float* Fk_b = Fk + (size_t)b * LK * DD;
  const float* V_b = V + (size_t)b * LK * DD;

  // load Q tile (16 x 256): thread t -> float4 #(t&63) of rows (t>>6)+4i
  {
    const int r = tid >> 6;
    const int c4 = (tid & 63) * 4;
#pragma unroll
    for (int i = 0; i < 4; ++i) {
      *(float4*)&Qs[r + 4 * i][c4] =
          *(const float4*)&Fq_b[(size_t)(r + 4 * i) * DD + c4];
    }
  }

  float m_run = -1e30f;
  float l_run = 0.f;
  float acc[4][4] = {};  // d = c*64 + g*4 + j

  for (int q0 = 0; q0 < LK; q0 += AT_T) {
    {
      const int r = tid >> 6;
      const int c4 = (tid & 63) * 4;
#pragma unroll
      for (int i = 0; i < 4; ++i) {
        *(float4*)&Ks[r + 4 * i][c4] =
            *(const float4*)&Fk_b[(size_t)(q0 + r + 4 * i) * DD + c4];
        *(float4*)&Vs[r + 4 * i][c4] =
            *(const float4*)&V_b[(size_t)(q0 + r + 4 * i) * DD + c4];
      }
    }
    __syncthreads();

    // score: e = dot(Qs[p], Ks[g]) over 256
    float e = 0.f;
#pragma unroll 8
    for (int k = 0; k < DD; k += 4) {
      float4 qv = *(const float4*)&Qs[p][k];
      float4 kv = *(const float4*)&Ks[g][k];
      e += qv.x * kv.x + qv.y * kv.y + qv.z * kv.z + qv.w * kv.w;
    }

    // online softmax within the 16-lane row group (contiguous lanes in a wave)
    float tile_max = e;
#pragma unroll
    for (int off = 1; off < 16; off <<= 1)
      tile_max = fmaxf(tile_max, __shfl_xor(tile_max, off, 64));
    const float m_new = fmaxf(m_run, tile_max);
    const float pexp = __expf(e - m_new);
    float tile_sum = pexp;
#pragma unroll
    for (int off = 1; off < 16; off <<= 1)
      tile_sum += __shfl_xor(tile_sum, off, 64);
    const float alpha = __expf(m_run - m_new);
    l_run = l_run * alpha + tile_sum;
    m_run = m_new;
    Ss[p][g] = pexp;

#pragma unroll
    for (int c = 0; c < 4; ++c)
#pragma unroll
      for (int j = 0; j < 4; ++j) acc[c][j] *= alpha;
    __syncthreads();  // Ss visible (cross-wave safety), tiles still live

    // PV: acc[c][j] += sum_q Ss[p][q] * Vs[q][c*64+g*4+j]
#pragma unroll
    for (int q = 0; q < AT_T; ++q) {
      const float pq = Ss[p][q];
#pragma unroll
      for (int c = 0; c < 4; ++c) {
        float4 vv = *(const float4*)&Vs[q][c * 64 + g * 4];
        acc[c][0] += pq * vv.x;
        acc[c][1] += pq * vv.y;
        acc[c][2] += pq * vv.z;
        acc[c][3] += pq * vv.w;
      }
    }
    __syncthreads();  // done with Ks/Vs/Ss before next-iter overwrite
  }

  const float inv_l = 1.f / l_run;
  float* out_row = Out + ((size_t)b * LQ + p0 + p) * DD;
#pragma unroll
  for (int c = 0; c < 4; ++c) {
    float4 o = make_float4(acc[c][0] * inv_l, acc[c][1] * inv_l,
                           acc[c][2] * inv_l, acc[c][3] * inv_l);
    *(float4*)&out_row[c * 64 + g * 4] = o;
  }
}

// ---------------------------------------------------------------------------
extern "C" void kernel_launch(void* const* d_in, const int* in_sizes, int n_in,
                              void* d_out, int out_size, void* d_ws,
                              size_t ws_size, hipStream_t stream) {
  const float* premises = (const float*)d_in[0];    // [32,1024,256]
  const float* hypotheses = (const float*)d_in[1];  // [32,1024,256]
  const float* W = (const float*)d_in[2];           // [256,256]
  float* out = (float*)d_out;

  const size_t M = (size_t)BB * LPQ;  // 32768 rows each
  float* Fp = (float*)d_ws;           // [32768,256] fp32 = 33.55 MB
  float* Fh = Fp + M * DD;            // another 33.55 MB

  dim3 pgrid(M / PROJ_BM, DD / PROJ_BN);  // (512, 4)
  proj_tanh<<<pgrid, 256, 0, stream>>>(premises, W, Fp, (int)M);
  proj_tanh<<<pgrid, 256, 0, stream>>>(hypotheses, W, Fh, (int)M);

  const int nblk = BB * (LPQ / AT_T);  // 2048
  // betas: Q=F_p, K=F_h, V=hypotheses
  flash_attn<<<nblk, 256, 0, stream>>>(Fp, Fh, hypotheses, out, LPQ, LPQ);
  // alphas: Q=F_h, K=F_p, V=premises
  flash_attn<<<nblk, 256, 0, stream>>>(Fh, Fp, premises,
                                       out + (size_t)BB * LPQ * DD, LPQ, LPQ);
}

// Round 3
// 432.318 us; speedup vs baseline: 5.0821x; 5.0821x over previous
//
#include <hip/hip_runtime.h>

typedef _Float16 f16;
typedef __attribute__((ext_vector_type(8))) _Float16 f16x8;  // MFMA A/B frag (4 VGPRs)
typedef __attribute__((ext_vector_type(4))) _Float16 f16x4;
typedef __attribute__((ext_vector_type(4))) float f32x4;     // MFMA C/D frag

#define BB 32
#define LL 1024
#define DD 256

// ---------------------------------------------------------------------------
// Transpose + fp32->fp16: Y[b][d][l] = f16(X[b][l][d]).  Tile 64x64.
// Two inputs folded into one launch via blockIdx.z.
// ---------------------------------------------------------------------------
__global__ __launch_bounds__(256) void transpose_to_f16(
    const float* __restrict__ X0, f16* __restrict__ Y0,
    const float* __restrict__ X1, f16* __restrict__ Y1,
    int L, int D, int nbPerInput) {
  __shared__ float T[64][68];
  const int tid = threadIdx.x;
  int bz = blockIdx.z;
  const float* X = X0;
  f16* Y = Y0;
  int b = bz;
  if (bz >= nbPerInput) { X = X1; Y = Y1; b = bz - nbPerInput; }
  const int l0 = blockIdx.x * 64, d0 = blockIdx.y * 64;
  const size_t baseX = (size_t)b * L * D;
#pragma unroll
  for (int pass = 0; pass < 4; ++pass) {
    int r = (tid >> 4) + pass * 16;
    int c = (tid & 15) * 4;
    float4 v = *(const float4*)&X[baseX + (size_t)(l0 + r) * D + d0 + c];
    *(float4*)&T[r][c] = v;
  }
  __syncthreads();
  const size_t baseY = (size_t)b * D * L;
#pragma unroll
  for (int pass = 0; pass < 2; ++pass) {
    int dr = (tid >> 3) + pass * 32;
    int lc = (tid & 7) * 8;
    f16x8 o;
#pragma unroll
    for (int j = 0; j < 8; ++j) o[j] = (f16)T[lc + j][dr];
    *(f16x8*)&Y[baseY + (size_t)(d0 + dr) * L + l0 + lc] = o;
  }
}

// ---------------------------------------------------------------------------
// Projection: F = tanh(A @ W), A fp32 [32768,256], Wt f16 [256][256] (=W^T),
// F f16 [32768,256].  Block: 256 thr = 4 waves, tile 64m x 64n, MFMA 16x16x32.
// grid (512, 4, 2) — z selects premises/hypotheses.
// ---------------------------------------------------------------------------
__global__ __launch_bounds__(256, 3) void proj_mfma(
    const float* __restrict__ Pin, const float* __restrict__ Hin,
    const f16* __restrict__ Wt, f16* __restrict__ Fp, f16* __restrict__ Fh) {
  __shared__ f16 Wts[64][264];  // rows: n (h), cols: k (d); +8 pad
  __shared__ f16 As[64][72];    // rows: m, cols: 64 k f16; +8 pad
  const int tid = threadIdx.x;
  const int wv = tid >> 6, lane = tid & 63, quad = lane >> 4, l16 = lane & 15;
  const float* A = blockIdx.z ? Hin : Pin;
  f16* F = blockIdx.z ? Fh : Fp;
  const int m0 = blockIdx.x * 64, n0 = blockIdx.y * 64;

  // stage Wt rows [n0, n0+64)
#pragma unroll
  for (int pass = 0; pass < 8; ++pass) {
    int row = (tid >> 5) + pass * 8;
    int chunk = tid & 31;
    *(f16x8*)&Wts[row][chunk * 8] =
        *(const f16x8*)&Wt[(size_t)(n0 + row) * 256 + chunk * 8];
  }

  f32x4 acc[4] = {};
  const int ar = tid >> 2, aq = tid & 3;
  for (int kc = 0; kc < 4; ++kc) {  // k-chunks of 64
    __syncthreads();                // As free
    const float* arow = A + (size_t)(m0 + ar) * 256 + kc * 64 + aq * 16;
#pragma unroll
    for (int i = 0; i < 4; ++i) {
      float4 v = *(const float4*)&arow[i * 4];
      f16x4 bv;
      bv[0] = (f16)v.x; bv[1] = (f16)v.y; bv[2] = (f16)v.z; bv[3] = (f16)v.w;
      *(f16x4*)&As[ar][aq * 16 + i * 4] = bv;
    }
    __syncthreads();  // As (and on 1st iter Wts) visible
#pragma unroll
    for (int s = 0; s < 2; ++s) {  // k-steps of 32
      f16x8 af = *(const f16x8*)&As[wv * 16 + l16][s * 32 + quad * 8];
#pragma unroll
      for (int t = 0; t < 4; ++t) {
        f16x8 wf = *(const f16x8*)&Wts[t * 16 + l16][kc * 64 + s * 32 + quad * 8];
        acc[t] = __builtin_amdgcn_mfma_f32_16x16x32_f16(af, wf, acc[t], 0, 0, 0);
      }
    }
  }

  // tanh epilogue + f16 store.  C layout: row = quad*4+reg, col = lane&15.
#pragma unroll
  for (int t = 0; t < 4; ++t)
#pragma unroll
    for (int r = 0; r < 4; ++r) {
      float x = acc[t][r];
      float e = __expf(2.f * x);          // inf for huge x -> tanh -> 1 (correct)
      float th = 1.f - 2.f / (e + 1.f);
      F[(size_t)(m0 + wv * 16 + quad * 4 + r) * 256 + n0 + t * 16 + l16] =
          (f16)th;
    }
}

// ---------------------------------------------------------------------------
// Flash alignment, MFMA: Out[b,p,:] = softmax_q(Fq[b,p]·Fk[b,q]) @ V.
// Block: 256 thr = 4 waves; TQ=64 (wave owns 16 p-rows), TK=32.
// Q frags in registers; K rows + V^T rows in LDS (+16B pad); P via LDS.
// grid (512, 2) — y selects betas/alphas direction.
// ---------------------------------------------------------------------------
__global__ __launch_bounds__(256, 3) void flash_mfma(
    const f16* __restrict__ Fpm, const f16* __restrict__ Fhm,
    const f16* __restrict__ Vth, const f16* __restrict__ Vtp,
    float* __restrict__ Out) {
  __shared__ f16 Ks[32][264];   // K rows: 256 f16 + 8 pad   (16896 B)
  __shared__ f16 Vs[256][40];   // V^T rows: 32 q f16 + 8 pad (20480 B)
  __shared__ f16 Ps[64][40];    // P rows: 32 q f16 + 8 pad   (5120 B)

  const int tid = threadIdx.x;
  const int wv = tid >> 6, lane = tid & 63, quad = lane >> 4, l16 = lane & 15;

  const f16* Fq = Fpm; const f16* Fk = Fhm; const f16* Vt = Vth;
  float* O = Out;
  if (blockIdx.y) { Fq = Fhm; Fk = Fpm; Vt = Vtp; O = Out + (size_t)BB * LL * DD; }

  const int b = blockIdx.x >> 4;
  const int p0 = (blockIdx.x & 15) * 64;

  const f16* Fq_b = Fq + ((size_t)b * LL + p0) * DD;
  const f16* Fk_b = Fk + (size_t)b * LL * DD;
  const f16* Vt_b = Vt + (size_t)b * DD * LL;

  // preload the wave's Q fragments (16 p-rows x 256 d) into registers
  f16x8 qf[8];
  {
    const f16* qrow = Fq_b + (size_t)(wv * 16 + l16) * DD + quad * 8;
#pragma unroll
    for (int s = 0; s < 8; ++s) qf[s] = *(const f16x8*)&qrow[s * 32];
  }

  float m_run[4], l_run[4];
#pragma unroll
  for (int r = 0; r < 4; ++r) { m_run[r] = -1e30f; l_run[r] = 0.f; }
  f32x4 o[16];
#pragma unroll
  for (int t = 0; t < 16; ++t) o[t] = (f32x4){0.f, 0.f, 0.f, 0.f};

  for (int q0 = 0; q0 < LL; q0 += 32) {
    __syncthreads();  // prev compute done; Ks/Vs reusable
    {
      // K tile: 32 rows x 512B
      int row = tid >> 5, chunk = tid & 31;
#pragma unroll
      for (int pass = 0; pass < 4; ++pass)
        *(f16x8*)&Ks[row + pass * 8][chunk * 8] =
            *(const f16x8*)&Fk_b[(size_t)(q0 + row + pass * 8) * DD + chunk * 8];
      // V^T tile: 256 d-rows x 64B
      int d = tid >> 2, ch = tid & 3;
#pragma unroll
      for (int pass = 0; pass < 4; ++pass)
        *(f16x8*)&Vs[d + pass * 64][ch * 8] =
            *(const f16x8*)&Vt_b[(size_t)(d + pass * 64) * LL + q0 + ch * 8];
    }
    __syncthreads();  // staging visible

    // S = Q K^T  (two 16-col subtiles)
    f32x4 s0 = {0.f, 0.f, 0.f, 0.f}, s1 = {0.f, 0.f, 0.f, 0.f};
#pragma unroll
    for (int s = 0; s < 8; ++s) {
      f16x8 k0 = *(const f16x8*)&Ks[l16][s * 32 + quad * 8];
      f16x8 k1 = *(const f16x8*)&Ks[16 + l16][s * 32 + quad * 8];
      s0 = __builtin_amdgcn_mfma_f32_16x16x32_f16(qf[s], k0, s0, 0, 0, 0);
      s1 = __builtin_amdgcn_mfma_f32_16x16x32_f16(qf[s], k1, s1, 0, 0, 0);
    }

    // online softmax across the 32 kv cols.  C layout: row=quad*4+r, col=l16.
    float alpha[4];
#pragma unroll
    for (int r = 0; r < 4; ++r) {
      float mt = fmaxf(s0[r], s1[r]);
#pragma unroll
      for (int off = 1; off < 16; off <<= 1)
        mt = fmaxf(mt, __shfl_xor(mt, off, 64));
      float mn = fmaxf(m_run[r], mt);
      float e0 = __expf(s0[r] - mn);
      float e1 = __expf(s1[r] - mn);
      float su = e0 + e1;
#pragma unroll
      for (int off = 1; off < 16; off <<= 1)
        su += __shfl_xor(su, off, 64);
      float a = __expf(m_run[r] - mn);
      l_run[r] = l_run[r] * a + su;
      m_run[r] = mn;
      alpha[r] = a;
      int prow = wv * 16 + quad * 4 + r;
      Ps[prow][l16] = (f16)e0;        // wave-private rows: no barrier needed
      Ps[prow][16 + l16] = (f16)e1;
    }

    // rescale O by alpha (per p-row)
#pragma unroll
    for (int t = 0; t < 16; ++t) {
      o[t][0] *= alpha[0]; o[t][1] *= alpha[1];
      o[t][2] *= alpha[2]; o[t][3] *= alpha[3];
    }

    // O += P V : A = P (16x32), B = V^T rows (q contiguous)
    f16x8 pf = *(const f16x8*)&Ps[wv * 16 + l16][quad * 8];
#pragma unroll
    for (int t = 0; t < 16; ++t) {
      f16x8 vf = *(const f16x8*)&Vs[t * 16 + l16][quad * 8];
      o[t] = __builtin_amdgcn_mfma_f32_16x16x32_f16(pf, vf, o[t], 0, 0, 0);
    }
  }

  // epilogue: normalize and store fp32
  float inv[4];
#pragma unroll
  for (int r = 0; r < 4; ++r) inv[r] = 1.f / l_run[r];
#pragma unroll
  for (int t = 0; t < 16; ++t)
#pragma unroll
    for (int r = 0; r < 4; ++r)
      O[(size_t)((size_t)b * LL + p0 + wv * 16 + quad * 4 + r) * DD + t * 16 +
        l16] = o[t][r] * inv[r];
}

// ---------------------------------------------------------------------------
extern "C" void kernel_launch(void* const* d_in, const int* in_sizes, int n_in,
                              void* d_out, int out_size, void* d_ws,
                              size_t ws_size, hipStream_t stream) {
  const float* premises = (const float*)d_in[0];    // [32,1024,256] fp32
  const float* hypotheses = (const float*)d_in[1];  // [32,1024,256] fp32
  const float* W = (const float*)d_in[2];           // [256,256] fp32
  float* out = (float*)d_out;

  const size_t MF = (size_t)BB * LL * DD;  // 8388608 elements
  f16* Fp = (f16*)d_ws;       // f16 F_p  (16.78 MB)
  f16* Fh = Fp + MF;          // f16 F_h
  f16* Vth = Fh + MF;         // f16 hypotheses^T [B][D][L]
  f16* Vtp = Vth + MF;        // f16 premises^T   [B][D][L]
  // ws is exactly 64 MiB full; stash Wt (131 KB) in the tail of d_out —
  // used only by proj_mfma, then fully overwritten by flash_mfma.
  f16* Wt = (f16*)((char*)d_out + (size_t)out_size * 4 - 256 * 256 * 2);

  // W^T -> f16 (tiny)
  transpose_to_f16<<<dim3(4, 4, 1), 256, 0, stream>>>(W, Wt, W, Wt, 256, 256, 1);
  // hypotheses^T and premises^T -> f16
  transpose_to_f16<<<dim3(16, 4, 64), 256, 0, stream>>>(
      hypotheses, Vth, premises, Vtp, LL, DD, BB);
  // F_p, F_h = tanh(X @ W) in f16
  proj_mfma<<<dim3(512, 4, 2), 256, 0, stream>>>(premises, hypotheses, Wt, Fp, Fh);
  // betas (y=0) and alphas (y=1)
  flash_mfma<<<dim3(512, 2), 256, 0, stream>>>(Fp, Fh, Vth, Vtp, out);
}

// Round 5
// 257.622 us; speedup vs baseline: 8.5283x; 1.6781x over previous
//
#include <hip/hip_runtime.h>

typedef _Float16 f16;
typedef __attribute__((ext_vector_type(4))) _Float16 f16x4;
typedef __attribute__((ext_vector_type(8))) _Float16 f16x8;
typedef __attribute__((ext_vector_type(4))) float f32x4;
typedef __attribute__((ext_vector_type(16))) float f32x16;
typedef unsigned int u32;

#define BB 32
#define LL 1024
#define DD 256

// async global->LDS, 16B per lane, dst = ldsbase + lane*16 (wave-uniform base)
__device__ __forceinline__ void async_copy16(const f16* g, f16* l) {
  __builtin_amdgcn_global_load_lds(
      (const __attribute__((address_space(1))) u32*)(const void*)g,
      (__attribute__((address_space(3))) u32*)(void*)l, 16, 0, 0);
}

// pack two f32 -> f16x2 in a u32 (v_cvt_pkrtz_f16_f32)
__device__ __forceinline__ u32 pack_pkrtz(float a, float b) {
  auto pk = __builtin_amdgcn_cvt_pkrtz(a, b);  // __fp16 ext_vector(2)
  u32 w;
  __builtin_memcpy(&w, &pk, 4);
  return w;
}

// ---------------------------------------------------------------------------
// Transpose + fp32->fp16 (used only for the tiny W^T).
// ---------------------------------------------------------------------------
__global__ __launch_bounds__(256) void transpose_to_f16(
    const float* __restrict__ X0, f16* __restrict__ Y0,
    const float* __restrict__ X1, f16* __restrict__ Y1,
    int L, int D, int nbPerInput) {
  __shared__ float T[64][68];
  const int tid = threadIdx.x;
  int bz = blockIdx.z;
  const float* X = X0;
  f16* Y = Y0;
  int b = bz;
  if (bz >= nbPerInput) { X = X1; Y = Y1; b = bz - nbPerInput; }
  const int l0 = blockIdx.x * 64, d0 = blockIdx.y * 64;
  const size_t baseX = (size_t)b * L * D;
#pragma unroll
  for (int pass = 0; pass < 4; ++pass) {
    int r = (tid >> 4) + pass * 16;
    int c = (tid & 15) * 4;
    float4 v = *(const float4*)&X[baseX + (size_t)(l0 + r) * D + d0 + c];
    *(float4*)&T[r][c] = v;
  }
  __syncthreads();
  const size_t baseY = (size_t)b * D * L;
#pragma unroll
  for (int pass = 0; pass < 2; ++pass) {
    int dr = (tid >> 3) + pass * 32;
    int lc = (tid & 7) * 8;
    f16x8 o;
#pragma unroll
    for (int j = 0; j < 8; ++j) o[j] = (f16)T[lc + j][dr];
    *(f16x8*)&Y[baseY + (size_t)(d0 + dr) * L + l0 + lc] = o;
  }
}

// ---------------------------------------------------------------------------
// Projection: F = tanh(A @ W)  (f16 out)  +  fused X^T f16 write.
// Block: 256 thr = 4 waves, tile 64m x 64n, MFMA 16x16x32.
// y-block y also emits X^T k-chunk y from its staged/converted A tile,
// replacing the standalone input-transpose kernel.
// ---------------------------------------------------------------------------
__global__ __launch_bounds__(256, 3) void proj_mfma(
    const float* __restrict__ Pin, const float* __restrict__ Hin,
    const f16* __restrict__ Wt, f16* __restrict__ Fp, f16* __restrict__ Fh,
    f16* __restrict__ Vtp, f16* __restrict__ Vth) {
  __shared__ f16 Wts[64][264];
  __shared__ f16 As[64][72];
  const int tid = threadIdx.x;
  const int wv = tid >> 6, lane = tid & 63, quad = lane >> 4, l16 = lane & 15;
  const float* A = blockIdx.z ? Hin : Pin;
  f16* F = blockIdx.z ? Fh : Fp;
  f16* VtO = blockIdx.z ? Vth : Vtp;
  const int m0 = blockIdx.x * 64, n0 = blockIdx.y * 64;

#pragma unroll
  for (int pass = 0; pass < 8; ++pass) {
    int row = (tid >> 5) + pass * 8;
    int chunk = tid & 31;
    *(f16x8*)&Wts[row][chunk * 8] =
        *(const f16x8*)&Wt[(size_t)(n0 + row) * 256 + chunk * 8];
  }

  f32x4 acc[4] = {};
  const int ar = tid >> 2, aq = tid & 3;
  for (int kc = 0; kc < 4; ++kc) {  // k-chunks of 64
    __syncthreads();
    const float* arow = A + (size_t)(m0 + ar) * 256 + kc * 64 + aq * 16;
#pragma unroll
    for (int i = 0; i < 4; ++i) {
      float4 v = *(const float4*)&arow[i * 4];
      f16x4 bv;
      bv[0] = (f16)v.x; bv[1] = (f16)v.y; bv[2] = (f16)v.z; bv[3] = (f16)v.w;
      *(f16x4*)&As[ar][aq * 16 + i * 4] = bv;
    }
    __syncthreads();
#pragma unroll
    for (int s = 0; s < 2; ++s) {
      f16x8 af = *(const f16x8*)&As[wv * 16 + l16][s * 32 + quad * 8];
#pragma unroll
      for (int t = 0; t < 4; ++t) {
        f16x8 wf = *(const f16x8*)&Wts[t * 16 + l16][kc * 64 + s * 32 + quad * 8];
        acc[t] = __builtin_amdgcn_mfma_f32_16x16x32_f16(af, wf, acc[t], 0, 0, 0);
      }
    }
    // fused X^T emit: y-block kc writes d = kc*64+dd, l-range of this m-tile
    if ((int)blockIdx.y == kc) {
      int dd = tid & 63, lg = tid >> 6;
      int bI = m0 >> 10, l_base = m0 & 1023;
      f16* vrow = VtO + (size_t)bI * DD * LL + (size_t)(kc * 64 + dd) * LL + l_base;
#pragma unroll
      for (int part = 0; part < 2; ++part) {
        int lo = lg * 16 + part * 8;
        f16x8 ov;
#pragma unroll
        for (int j = 0; j < 8; ++j) ov[j] = As[lo + j][dd];
        *(f16x8*)&vrow[lo] = ov;
      }
    }
  }

#pragma unroll
  for (int t = 0; t < 4; ++t)
#pragma unroll
    for (int r = 0; r < 4; ++r) {
      float x = acc[t][r];
      float e = __expf(2.f * x);
      float th = 1.f - 2.f / (e + 1.f);
      F[(size_t)(m0 + wv * 16 + quad * 4 + r) * 256 + n0 + t * 16 + l16] =
          (f16)th;
    }
}

// ---------------------------------------------------------------------------
// Flash alignment, 32x32x16 MFMA, transposed formulation:
//   S^T = K Q^T  (A=K frags from LDS, B=Q frags in regs)
//   O^T = V^T P^T (A=V^T frags from LDS, B=P^T built by cross-half shuffle)
// Wave owns 32 p-columns (p = lane&31); in-lane softmax + 1 shfl_xor(32).
// LDS 32 KB fragment-order, staged via global_load_lds(16B). 2 blocks/CU.
// ---------------------------------------------------------------------------
__global__ __launch_bounds__(256, 2) void flash_mfma(
    const f16* __restrict__ Fpm, const f16* __restrict__ Fhm,
    const f16* __restrict__ Vth, const f16* __restrict__ Vtp,
    float* __restrict__ Out) {
  __shared__ f16 Kf[16][512];  // K frag s: lane -> K[q0+l32][s*16+half*8 ..+8]
  __shared__ f16 Vf[16][512];  // V frag v=t*2+h: lane -> V^T[t*32+l32][q0+h*16+half*8 ..+8]

  const int tid = threadIdx.x;
  const int wv = tid >> 6, lane = tid & 63;
  const int l32 = lane & 31, half = lane >> 5;

  const f16* Fq = Fpm;
  const f16* Fk = Fhm;
  const f16* Vt = Vth;
  float* O = Out;
  if (blockIdx.y) { Fq = Fhm; Fk = Fpm; Vt = Vtp; O = Out + (size_t)BB * LL * DD; }

  const int b = blockIdx.x >> 3;
  const int p0 = (blockIdx.x & 7) * 128 + wv * 32;
  const int p = p0 + l32;  // this lane's p-column

  const f16* Fq_b = Fq + (size_t)b * LL * DD;
  const f16* Fk_b = Fk + (size_t)b * LL * DD;
  const f16* Vt_b = Vt + (size_t)b * DD * LL;

  // Q fragments (B-operand): n=p=l32, k=half*8+j, 16 k-steps of 16
  f16x8 qf[16];
  {
    const f16* qrow = Fq_b + (size_t)p * DD + half * 8;
#pragma unroll
    for (int s = 0; s < 16; ++s) qf[s] = *(const f16x8*)&qrow[s * 16];
  }

  float m_run = -1e30f, l_run = 0.f;
  f32x16 o[8];
#pragma unroll
  for (int t = 0; t < 8; ++t) o[t] = (f32x16)(0.f);

  for (int q0 = 0; q0 < LL; q0 += 32) {
    __syncthreads();  // previous tile's LDS reads complete
    // stage: wave wv loads K frags wv*4..+3 and V frags wv*4..+3
#pragma unroll
    for (int i = 0; i < 4; ++i) {
      int s = wv * 4 + i;
      async_copy16(Fk_b + (size_t)(q0 + l32) * DD + s * 16 + half * 8, &Kf[s][0]);
    }
#pragma unroll
    for (int i = 0; i < 4; ++i) {
      int v = wv * 4 + i;
      int t = v >> 1, h = v & 1;
      async_copy16(Vt_b + (size_t)(t * 32 + l32) * LL + q0 + h * 16 + half * 8,
                   &Vf[v][0]);
    }
    __syncthreads();  // DMA landed (vmcnt drained at barrier)

    // S^T[q][p]: A = K frag (m=q), B = Q frag (n=p)
    f32x16 S = (f32x16)(0.f);
#pragma unroll
    for (int s = 0; s < 16; ++s) {
      f16x8 kf = *(const f16x8*)&Kf[s][lane * 8];  // conflict-free b128
      S = __builtin_amdgcn_mfma_f32_32x32x16_f16(kf, qf[s], S, 0, 0, 0);
    }

    // in-lane softmax: lane holds 16 q-values of its p; merge with other half
    float mt = S[0];
#pragma unroll
    for (int r = 1; r < 16; ++r) mt = fmaxf(mt, S[r]);
    mt = fmaxf(mt, __shfl_xor(mt, 32, 64));
    const float mn = fmaxf(m_run, mt);
    float pe[16];
    float ts = 0.f;
#pragma unroll
    for (int r = 0; r < 16; ++r) {
      pe[r] = __expf(S[r] - mn);
      ts += pe[r];
    }
    ts += __shfl_xor(ts, 32, 64);
    const float alpha = __expf(m_run - mn);
    l_run = l_run * alpha + ts;
    m_run = mn;

    // build P^T B-frags: pack f16 pairs, exchange cross-half (4 shfl)
    u32 pw[8];
#pragma unroll
    for (int i = 0; i < 8; ++i) pw[i] = pack_pkrtz(pe[2 * i], pe[2 * i + 1]);
    u32 rc[4];
    {
      u32 s0 = half ? pw[0] : pw[2];
      u32 s1 = half ? pw[1] : pw[3];
      u32 s2 = half ? pw[4] : pw[6];
      u32 s3 = half ? pw[5] : pw[7];
      rc[0] = (u32)__shfl_xor((int)s0, 32, 64);
      rc[1] = (u32)__shfl_xor((int)s1, 32, 64);
      rc[2] = (u32)__shfl_xor((int)s2, 32, 64);
      rc[3] = (u32)__shfl_xor((int)s3, 32, 64);
    }
    f16x8 pf[2];
#pragma unroll
    for (int h = 0; h < 2; ++h) {
      u32 tmp[4];
      tmp[0] = half ? rc[2 * h] : pw[4 * h];
      tmp[1] = half ? rc[2 * h + 1] : pw[4 * h + 1];
      tmp[2] = half ? pw[4 * h + 2] : rc[2 * h];
      tmp[3] = half ? pw[4 * h + 3] : rc[2 * h + 1];
      __builtin_memcpy(&pf[h], tmp, 16);
    }

    // rescale O^T, then O^T += V^T P^T
#pragma unroll
    for (int t = 0; t < 8; ++t)
#pragma unroll
      for (int r = 0; r < 16; ++r) o[t][r] *= alpha;
#pragma unroll
    for (int t = 0; t < 8; ++t) {
      f16x8 v0 = *(const f16x8*)&Vf[t * 2][lane * 8];
      o[t] = __builtin_amdgcn_mfma_f32_32x32x16_f16(v0, pf[0], o[t], 0, 0, 0);
      f16x8 v1 = *(const f16x8*)&Vf[t * 2 + 1][lane * 8];
      o[t] = __builtin_amdgcn_mfma_f32_32x32x16_f16(v1, pf[1], o[t], 0, 0, 0);
    }
  }

  // epilogue: C row = (r&3) + 8*(r>>2) + 4*half; col = p.  Pack 4 consecutive d.
  const float inv = 1.f / l_run;
  float* orow = O + ((size_t)b * LL + p) * DD;
#pragma unroll
  for (int t = 0; t < 8; ++t) {
#pragma unroll
    for (int g = 0; g < 4; ++g) {
      f32x4 v;
      v[0] = o[t][4 * g + 0] * inv;
      v[1] = o[t][4 * g + 1] * inv;
      v[2] = o[t][4 * g + 2] * inv;
      v[3] = o[t][4 * g + 3] * inv;
      *(f32x4*)&orow[t * 32 + 8 * g + 4 * half] = v;
    }
  }
}

// ---------------------------------------------------------------------------
extern "C" void kernel_launch(void* const* d_in, const int* in_sizes, int n_in,
                              void* d_out, int out_size, void* d_ws,
                              size_t ws_size, hipStream_t stream) {
  const float* premises = (const float*)d_in[0];    // [32,1024,256] fp32
  const float* hypotheses = (const float*)d_in[1];  // [32,1024,256] fp32
  const float* W = (const float*)d_in[2];           // [256,256] fp32
  float* out = (float*)d_out;

  const size_t MF = (size_t)BB * LL * DD;
  f16* Fp = (f16*)d_ws;   // 16 MiB each; ws = 64 MiB exactly
  f16* Fh = Fp + MF;
  f16* Vth = Fh + MF;     // hypotheses^T [B][D][L] f16
  f16* Vtp = Vth + MF;    // premises^T   [B][D][L] f16
  // Wt (131 KB) stashed in d_out tail: used only by proj, overwritten by flash
  f16* Wt = (f16*)((char*)d_out + (size_t)out_size * 4 - 256 * 256 * 2);

  // W^T -> f16
  transpose_to_f16<<<dim3(4, 4, 1), 256, 0, stream>>>(W, Wt, W, Wt, 256, 256, 1);
  // F = tanh(X @ W) f16, + fused X^T f16 emit (replaces big transpose kernel)
  proj_mfma<<<dim3(512, 4, 2), 256, 0, stream>>>(premises, hypotheses, Wt, Fp,
                                                 Fh, Vtp, Vth);
  // betas (y=0) and alphas (y=1): 256 blocks/direction, 2 blocks/CU exactly
  flash_mfma<<<dim3(256, 2), 256, 0, stream>>>(Fp, Fh, Vth, Vtp, out);
}